// Round 5
// baseline (1063.641 us; speedup 1.0000x reference)
//
#include <hip/hip_runtime.h>
#include <stdint.h>

#define NB 65536      // B rows
#define ND 256        // D
#define NK 2048       // K
#define NL 4          // L
#define THRM 0.012f   // accept margin for fp16 screening (score err max ~5e-3)

typedef _Float16 v8h __attribute__((ext_vector_type(8)));   // 8 fp16 (4 VGPR)
typedef __attribute__((ext_vector_type(4))) float v4f;      // MFMA acc
typedef unsigned long long ull;

// ---------------- zero the per-level uncertain counters ----------------
__global__ void k_zero(int* __restrict__ cnt) {
    if (threadIdx.x < NL) cnt[threadIdx.x] = 0;
}

// ---------------- e2: numpy-pairwise sum of emb^2 per row (validated r2) ----------------
// also writes e2n = -0.5*e2 (exact pow2 scale) for MFMA C-init folding
__global__ void k_e2(const float* __restrict__ cb, float* __restrict__ e2,
                     float* __restrict__ e2n) {
    __shared__ float tile[32 * 260];
    const int rowbase = blockIdx.x * 32;
    const float4* cb4 = (const float4*)(cb + (size_t)rowbase * ND);
    for (int it = 0; it < 32; ++it) {
        float4 v = cb4[it * 64 + threadIdx.x];
        *(float4*)&tile[it * 260 + threadIdx.x * 4] = v;
    }
    __syncthreads();
    if (threadIdx.x < 32) {
        const float* a = &tile[threadIdx.x * 260];
        float halves[2];
        for (int h = 0; h < 2; ++h) {
            const float* p = a + h * 128;
            float r8[8];
            #pragma unroll
            for (int j = 0; j < 8; ++j) r8[j] = __fmul_rn(p[j], p[j]);
            for (int i = 8; i < 128; i += 8) {
                #pragma unroll
                for (int j = 0; j < 8; ++j) r8[j] = __fadd_rn(r8[j], __fmul_rn(p[i + j], p[i + j]));
            }
            halves[h] = __fadd_rn(__fadd_rn(__fadd_rn(r8[0], r8[1]), __fadd_rn(r8[2], r8[3])),
                                  __fadd_rn(__fadd_rn(r8[4], r8[5]), __fadd_rn(r8[6], r8[7])));
        }
        const float s = __fadd_rn(halves[0], halves[1]);
        e2[rowbase + threadIdx.x] = s;
        e2n[rowbase + threadIdx.x] = -0.5f * s;
    }
}

// ---------------- convert codebooks to fp16 fragment-major ----------------
__global__ void k_split16(const float* __restrict__ cb, unsigned short* __restrict__ ehf) {
    const int f = blockIdx.x * 256 + threadIdx.x;     // 0 .. L*K*32
    const int g = f & 31;
    const int k = (f >> 5) & (NK - 1);
    const int l = f >> 16;
    const float* p = cb + ((size_t)(l * NK + k) * ND + g * 8);
    float4 a = *(const float4*)p;
    float4 b = *(const float4*)(p + 4);
    v8h h;
    h[0] = (_Float16)a.x; h[1] = (_Float16)a.y; h[2] = (_Float16)a.z; h[3] = (_Float16)a.w;
    h[4] = (_Float16)b.x; h[5] = (_Float16)b.y; h[6] = (_Float16)b.z; h[7] = (_Float16)b.w;
    const size_t u = (size_t)(k >> 4) * 512 + (g >> 2) * 64 + (g & 3) * 16 + (k & 15);
    *(v8h*)(void*)(ehf + (size_t)l * (NK * ND) + u * 8) = h;
}

// ---------------- residual -> fp16 fragment-major (bit-identical to old passA prologue) ----
// layout: resh[fid*8], fid = ((row>>4)*8 + dc)*64 + lane; row=(fid>>9)*16+(lane&15),
//         d = dc*32 + (lane>>4)*8
__global__ __launch_bounds__(256)
void k_res16(const float* __restrict__ residual,
             const float* __restrict__ cb,
             const int* __restrict__ idx_hist,
             unsigned short* __restrict__ resh,
             int level)
{
    const int fid = blockIdx.x * 256 + threadIdx.x;
    const int lane = fid & 63;
    const int dc = (fid >> 6) & 7;
    const int r16 = fid >> 9;
    const int row = r16 * 16 + (lane & 15);
    const int d0 = dc * 32 + (lane >> 4) * 8;
    const float* rp = residual + (size_t)row * ND + d0;
    float buf[8];
    *(float4*)&buf[0] = *(const float4*)rp;
    *(float4*)&buf[4] = *(const float4*)(rp + 4);
    for (int j = 0; j < level; ++j) {
        const int kp = idx_hist[j * NB + row];
        const float* qp = cb + ((size_t)(j * NK + kp) * ND + d0);
        #pragma unroll
        for (int c = 0; c < 8; ++c) buf[c] = __fsub_rn(buf[c], qp[c]);
    }
    v8h h;
    #pragma unroll
    for (int c = 0; c < 8; ++c) h[c] = (_Float16)buf[c];
    *(v8h*)(void*)(resh + (size_t)fid * 8) = h;
}

// ---------------- pass A: fp16 MFMA screening, split-K x4, e2 folded into C-init ----------
// tracks MAX of v = dot - 0.5*e2  (score = -2*v); converts at epilogue
// XCD-aware remap: 4 quarter-blocks of one row-tile land on the SAME XCD (L2 reuse of resh).
// B fragments read DIRECTLY from global (fragment-major ehf: each (nt,dc) frag is
// base + lane*16B, fully coalesced, L1/L2-resident). No LDS B-tile, no K-loop barriers:
// waves free-run, latency hidden wave-parallel.
__global__ __launch_bounds__(256)
void k_passA(const unsigned short* __restrict__ resh,
             const unsigned short* __restrict__ ehf,   // level slice, fragment-major
             const float* __restrict__ e2n,            // level slice, -0.5*e2
             float* __restrict__ pb1,                  // [4][B] best score
             int* __restrict__ pk1,                    // [4][B] best k
             float* __restrict__ ps2)                  // [4][B] second best
{
    __shared__ float e2t[512];

    const int tid = threadIdx.x;
    const int w = tid >> 6;
    const int lane = tid & 63;
    const int kloc = lane & 15;
    const int quad = lane >> 4;

    // remap: xcd = j&7 (HW round-robin), quarter cycles fastest within an XCD
    const int j = blockIdx.x;
    const int xcd = j & 7;
    const int within = j >> 3;                 // [0,256)
    const int quarter = within & 3;
    const int rowtile = xcd * 64 + (within >> 2);   // [0,512)
    const int rowbase = rowtile * 128 + w * 32;
    const int r16 = rowbase >> 4;

    // per-lane B stream base: fragment (kt,nt,dc) lives at bsrc[kt*1024 + (nt*8+dc)*64 + lane]
    const v8h* bsrc = (const v8h*)(const void*)(ehf + (size_t)quarter * (512 * ND));

    // A fragments: 16 coalesced 16B loads (prologue hoisted into k_res16)
    v8h ah[2][8];
    const v8h* rhp = (const v8h*)(const void*)resh;
    #pragma unroll
    for (int m = 0; m < 2; ++m) {
        #pragma unroll
        for (int dc = 0; dc < 8; ++dc)
            ah[m][dc] = rhp[((size_t)(r16 + m) * 8 + dc) * 64 + lane];
    }

    // -0.5*e2 slice for this K-quarter into LDS (broadcast reads, conflict-free)
    e2t[tid] = e2n[quarter * 512 + tid];
    e2t[256 + tid] = e2n[quarter * 512 + 256 + tid];

    float m1[8], m2[8];
    int k1[8];
    #pragma unroll
    for (int s = 0; s < 8; ++s) { m1[s] = -3.0e38f; m2[s] = -3.0e38f; k1[s] = 0; }

    __syncthreads();   // e2t visible (only barrier in the kernel)

    #pragma unroll 1
    for (int kt = 0; kt < 16; ++kt) {
        const v8h* bt = bsrc + (size_t)kt * 1024 + lane;
        #pragma unroll
        for (int nt = 0; nt < 2; ++nt) {
            const int klq = kt * 32 + nt * 16 + kloc;     // k within quarter
            const float e2h = e2t[klq];
            const v4f cinit = {e2h, e2h, e2h, e2h};
            v4f a0a, a1a;
            v4f a0b = {0.f, 0.f, 0.f, 0.f}, a1b = {0.f, 0.f, 0.f, 0.f};
            {
                const v8h bh = bt[(nt * 8 + 0) * 64];
                a0a = __builtin_amdgcn_mfma_f32_16x16x32_f16(ah[0][0], bh, cinit, 0, 0, 0);
                a1a = __builtin_amdgcn_mfma_f32_16x16x32_f16(ah[1][0], bh, cinit, 0, 0, 0);
            }
            #pragma unroll
            for (int dc = 1; dc < 4; ++dc) {
                const v8h bh = bt[(nt * 8 + dc) * 64];
                a0a = __builtin_amdgcn_mfma_f32_16x16x32_f16(ah[0][dc], bh, a0a, 0, 0, 0);
                a1a = __builtin_amdgcn_mfma_f32_16x16x32_f16(ah[1][dc], bh, a1a, 0, 0, 0);
            }
            #pragma unroll
            for (int dc = 4; dc < 8; ++dc) {
                const v8h bh = bt[(nt * 8 + dc) * 64];
                a0b = __builtin_amdgcn_mfma_f32_16x16x32_f16(ah[0][dc], bh, a0b, 0, 0, 0);
                a1b = __builtin_amdgcn_mfma_f32_16x16x32_f16(ah[1][dc], bh, a1b, 0, 0, 0);
            }
            const int kglob = quarter * 512 + klq;
            #pragma unroll
            for (int reg = 0; reg < 4; ++reg) {
                const float v0 = a0a[reg] + a0b[reg];
                const bool g0 = v0 > m1[reg];
                m2[reg] = __builtin_amdgcn_fmed3f(v0, m1[reg], m2[reg]);  // = max(m2, min(m1, v0))
                m1[reg] = fmaxf(m1[reg], v0);
                k1[reg] = g0 ? kglob : k1[reg];
                const float v1 = a1a[reg] + a1b[reg];
                const bool g1 = v1 > m1[4 + reg];
                m2[4 + reg] = __builtin_amdgcn_fmed3f(v1, m1[4 + reg], m2[4 + reg]);
                m1[4 + reg] = fmaxf(m1[4 + reg], v1);
                k1[4 + reg] = g1 ? kglob : k1[4 + reg];
            }
        }
    }

    // 16-lane max-reduction (tie-breaks irrelevant: within-THRM ties go to exact rerank)
    #pragma unroll
    for (int off = 1; off < 16; off <<= 1) {
        #pragma unroll
        for (int s = 0; s < 8; ++s) {
            const float o1 = __shfl_xor(m1[s], off, 16);
            const float o2 = __shfl_xor(m2[s], off, 16);
            const int   ok = __shfl_xor(k1[s], off, 16);
            const float lo = fminf(m1[s], o1);
            m2[s] = fmaxf(fmaxf(m2[s], o2), lo);
            k1[s] = (o1 > m1[s]) ? ok : k1[s];
            m1[s] = fmaxf(m1[s], o1);
        }
    }
    if (kloc == 0) {
        #pragma unroll
        for (int s = 0; s < 8; ++s) {
            const int m = s >> 2, reg = s & 3;
            const int row = rowbase + m * 16 + quad * 4 + reg;
            pb1[(size_t)quarter * NB + row] = -2.0f * m1[s];
            pk1[(size_t)quarter * NB + row] = k1[s];
            ps2[(size_t)quarter * NB + row] = -2.0f * m2[s];
        }
    }
}

// ---------------- merge 4 K-quarters (float compares — scores can be negative!) ----------
__global__ void k_margin(const float* __restrict__ pb1, const int* __restrict__ pk1,
                         const float* __restrict__ ps2,
                         int* __restrict__ idx_l, float* __restrict__ codes,
                         int* __restrict__ ulist, int* __restrict__ cnt, int level)
{
    const int row = blockIdx.x * 256 + threadIdx.x;
    float b1 = pb1[row];
    int   k  = pk1[row];
    float b2 = ps2[row];
    #pragma unroll
    for (int p = 1; p < 4; ++p) {
        const float c1 = pb1[(size_t)p * NB + row];
        const float c2 = ps2[(size_t)p * NB + row];
        const int   ck = pk1[(size_t)p * NB + row];
        if (c1 < b1) { b2 = fminf(b1, c2); b1 = c1; k = ck; }
        else         { b2 = fminf(b2, c1); }
    }
    idx_l[row] = k;
    codes[(size_t)row * NL + level] = (float)k;
    if (b2 - b1 <= THRM) {
        int p = atomicAdd(cnt, 1);
        ulist[p] = row;
    }
}

// ---------------- rerank stage 1: exact scores (bit-exact validated path) ----------------
// emb read direct from L2 (no 64KB LDS stage -> occupancy no longer LDS-capped);
// x2 via 16-lane shfl_xor butterfly reproducing the exact pairwise-sum tree.
__global__ __launch_bounds__(256)
void k_rr1(const float* __restrict__ residual,
           const float* __restrict__ cb,
           const float* __restrict__ emb,
           const float* __restrict__ e2,
           const int* __restrict__ idx_hist,
           const int* __restrict__ ulist,
           const int* __restrict__ cnt,
           ull* __restrict__ partial,
           int level)
{
    __shared__ float resL[16 * 260];
    __shared__ float x2s[16];
    __shared__ int   urows[16];
    __shared__ ull   redM[16][17];

    const int t = threadIdx.x;
    const int ks = blockIdx.x & 31;
    const int rt0 = blockIdx.x >> 5;
    const int n = *cnt;
    const int nrt = (n + 15) >> 4;
    if (rt0 >= nrt) return;

    const int row = t & 15;
    const int kg = t >> 4;
    float e2r[4];
    #pragma unroll
    for (int j = 0; j < 4; ++j) e2r[j] = e2[ks * 64 + kg * 4 + j];
    const float* ep = emb + (size_t)(ks * 64 + kg * 4) * ND;

    for (int rt = rt0; rt < nrt; rt += 64) {
        __syncthreads();
        if (t < 16) {
            const int i = rt * 16 + t;
            urows[t] = ulist[(i < n) ? i : rt * 16];
        }
        __syncthreads();
        #pragma unroll
        for (int i = 0; i < 4; ++i) {
            const int fi = t + 256 * i;
            const int r = fi >> 6, q = fi & 63;
            const int ur = urows[r];
            float4 v = ((const float4*)residual)[(size_t)ur * 64 + q];
            for (int j = 0; j < level; ++j) {
                const int kp = idx_hist[j * NB + ur];
                const float4 qv = ((const float4*)cb)[(size_t)(j * NK + kp) * 64 + q];
                v.x = __fsub_rn(v.x, qv.x);
                v.y = __fsub_rn(v.y, qv.y);
                v.z = __fsub_rn(v.z, qv.z);
                v.w = __fsub_rn(v.w, qv.w);
            }
            *(float4*)&resL[r * 260 + q * 4] = v;
        }
        __syncthreads();
        {
            // 16 lanes per row: lane (h, jj) owns accumulator r8[jj] of half h
            // (identical __fmul_rn/__fadd_rn chain), then xor-butterfly combines in
            // the exact tree order ((01)+(23))+((45)+(67)), then halves[0]+halves[1].
            const int xr = t >> 4;
            const int h = (t >> 3) & 1;
            const int jj = t & 7;
            const float* p = &resL[xr * 260 + h * 128];
            float v = __fmul_rn(p[jj], p[jj]);
            for (int i = 8; i < 128; i += 8)
                v = __fadd_rn(v, __fmul_rn(p[i + jj], p[i + jj]));
            v = __fadd_rn(v, __shfl_xor(v, 1, 16));
            v = __fadd_rn(v, __shfl_xor(v, 2, 16));
            v = __fadd_rn(v, __shfl_xor(v, 4, 16));
            v = __fadd_rn(v, __shfl_xor(v, 8, 16));
            if ((t & 15) == 0) x2s[xr] = v;
        }
        __syncthreads();

        float d0 = 0.f, d1 = 0.f, d2 = 0.f, d3 = 0.f;
        const float* rp = &resL[row * 260];
        #pragma unroll 4
        for (int q = 0; q < 64; ++q) {
            const float4 rv = *(const float4*)&rp[q * 4];
            const float4 e0 = *(const float4*)&ep[q * 4];
            const float4 e1 = *(const float4*)&ep[ND + q * 4];
            const float4 ee2 = *(const float4*)&ep[2 * ND + q * 4];
            const float4 e3 = *(const float4*)&ep[3 * ND + q * 4];
            d0 = __fmaf_rn(rv.x, e0.x, d0); d0 = __fmaf_rn(rv.y, e0.y, d0);
            d0 = __fmaf_rn(rv.z, e0.z, d0); d0 = __fmaf_rn(rv.w, e0.w, d0);
            d1 = __fmaf_rn(rv.x, e1.x, d1); d1 = __fmaf_rn(rv.y, e1.y, d1);
            d1 = __fmaf_rn(rv.z, e1.z, d1); d1 = __fmaf_rn(rv.w, e1.w, d1);
            d2 = __fmaf_rn(rv.x, ee2.x, d2); d2 = __fmaf_rn(rv.y, ee2.y, d2);
            d2 = __fmaf_rn(rv.z, ee2.z, d2); d2 = __fmaf_rn(rv.w, ee2.w, d2);
            d3 = __fmaf_rn(rv.x, e3.x, d3); d3 = __fmaf_rn(rv.y, e3.y, d3);
            d3 = __fmaf_rn(rv.z, e3.z, d3); d3 = __fmaf_rn(rv.w, e3.w, d3);
        }

        const float x2v = x2s[row];
        const int kb = ks * 64 + kg * 4;
        float s;
        ull best, u;
        s = __fsub_rn(__fadd_rn(x2v, e2r[0]), __fmul_rn(2.0f, d0));
        best = ((ull)__float_as_uint(s) << 32) | (ull)(kb + 0);
        s = __fsub_rn(__fadd_rn(x2v, e2r[1]), __fmul_rn(2.0f, d1));
        u = ((ull)__float_as_uint(s) << 32) | (ull)(kb + 1);
        if (u < best) best = u;
        s = __fsub_rn(__fadd_rn(x2v, e2r[2]), __fmul_rn(2.0f, d2));
        u = ((ull)__float_as_uint(s) << 32) | (ull)(kb + 2);
        if (u < best) best = u;
        s = __fsub_rn(__fadd_rn(x2v, e2r[3]), __fmul_rn(2.0f, d3));
        u = ((ull)__float_as_uint(s) << 32) | (ull)(kb + 3);
        if (u < best) best = u;

        redM[row][kg] = best;
        __syncthreads();
        if (t < 16) {
            ull b = redM[t][0];
            #pragma unroll
            for (int g = 1; g < 16; ++g) { const ull v = redM[t][g]; if (v < b) b = v; }
            partial[(size_t)(rt * 16 + t) * 32 + ks] = b;
        }
    }
}

// ---------------- rerank stage 2: reduce 32 k-slices per uncertain row ----------------
__global__ void k_rr2(const ull* __restrict__ partial,
                      const int* __restrict__ ulist,
                      const int* __restrict__ cnt,
                      int* __restrict__ idx_l,
                      float* __restrict__ codes,
                      int level)
{
    const int n = *cnt;
    for (int i = blockIdx.x * 256 + threadIdx.x; i < n; i += gridDim.x * 256) {
        const ull* p = &partial[(size_t)i * 32];
        ull b = p[0];
        #pragma unroll
        for (int s2 = 1; s2 < 32; ++s2) { const ull v = p[s2]; if (v < b) b = v; }
        const int k = (int)(b & 0xffffffffull);
        const int row = ulist[i];
        idx_l[row] = k;
        codes[(size_t)row * NL + level] = (float)k;
    }
}

// ---------------- finalize: quantized = fadd chain q0+q1+q2+q3 (reference order) ----------------
__global__ void k_finalize(const float* __restrict__ cb, const int* __restrict__ idx_hist,
                           float4* __restrict__ outq) {
    const int i = blockIdx.x * 256 + threadIdx.x;
    const int r = i >> 6, c = i & 63;
    const float4* cb4 = (const float4*)cb;
    const int i0 = idx_hist[r];
    const int i1 = idx_hist[NB + r];
    const int i2 = idx_hist[2 * NB + r];
    const int i3 = idx_hist[3 * NB + r];
    float4 q = cb4[(size_t)i0 * 64 + c];
    float4 t1 = cb4[(size_t)(NK + i1) * 64 + c];
    q.x = __fadd_rn(q.x, t1.x); q.y = __fadd_rn(q.y, t1.y);
    q.z = __fadd_rn(q.z, t1.z); q.w = __fadd_rn(q.w, t1.w);
    float4 t2 = cb4[(size_t)(2 * NK + i2) * 64 + c];
    q.x = __fadd_rn(q.x, t2.x); q.y = __fadd_rn(q.y, t2.y);
    q.z = __fadd_rn(q.z, t2.z); q.w = __fadd_rn(q.w, t2.w);
    float4 t3 = cb4[(size_t)(3 * NK + i3) * 64 + c];
    q.x = __fadd_rn(q.x, t3.x); q.y = __fadd_rn(q.y, t3.y);
    q.z = __fadd_rn(q.z, t3.z); q.w = __fadd_rn(q.w, t3.w);
    outq[i] = q;
}

extern "C" void kernel_launch(void* const* d_in, const int* in_sizes, int n_in,
                              void* d_out, int out_size, void* d_ws, size_t ws_size,
                              hipStream_t stream) {
    const float* residual = (const float*)d_in[0];
    const float* cb = (const float*)d_in[1];

    float* pb1 = (float*)d_ws;                                   // [4][B] 1 MB
    int* pk1 = (int*)(pb1 + 4 * (size_t)NB);                     // [4][B] 1 MB
    float* ps2 = (float*)(pk1 + 4 * (size_t)NB);                 // [4][B] 1 MB
    ull* partial = (ull*)(ps2 + 4 * (size_t)NB);                 // 16.8 MB
    float* e2 = (float*)(partial + (size_t)(NB + 16) * 32);      // 32 KB
    float* e2n = e2 + (size_t)NL * NK;                           // 32 KB
    int* idx_hist = (int*)(e2n + (size_t)NL * NK);               // [L][B] 1 MB
    int* ulist = idx_hist + (size_t)NL * NB;                     // 256 KB
    int* cnt = ulist + NB;
    unsigned short* ehf = (unsigned short*)(cnt + 64);           // fp16 frag-major 4 MB
    unsigned short* resh = ehf + (size_t)NL * NK * ND;           // fp16 residual frags 32 MB

    float* codes = (float*)d_out + (size_t)NB * ND;              // fp32 [B, L]

    k_zero<<<1, 64, 0, stream>>>(cnt);
    k_e2<<<NL * NK / 32, 64, 0, stream>>>(cb, e2, e2n);
    k_split16<<<NL * NK * 32 / 256, 256, 0, stream>>>(cb, ehf);

    for (int l = 0; l < NL; ++l) {
        const unsigned short* ehl = ehf + (size_t)l * NK * ND;
        const float* e2l = e2 + (size_t)l * NK;
        const float* e2nl = e2n + (size_t)l * NK;
        int* idx_l = idx_hist + (size_t)l * NB;
        k_res16<<<NB * ND / 8 / 256, 256, 0, stream>>>(residual, cb, idx_hist, resh, l);
        k_passA<<<NB / 128 * 4, 256, 0, stream>>>(resh, ehl, e2nl, pb1, pk1, ps2);
        k_margin<<<NB / 256, 256, 0, stream>>>(pb1, pk1, ps2, idx_l, codes, ulist, cnt + l, l);
        k_rr1<<<2048, 256, 0, stream>>>(residual, cb, cb + (size_t)l * NK * ND, e2l,
                                        idx_hist, ulist, cnt + l, partial, l);
        k_rr2<<<64, 256, 0, stream>>>(partial, ulist, cnt + l, idx_l, codes, l);
    }
    k_finalize<<<NB * ND / 4 / 256, 256, 0, stream>>>(cb, idx_hist, (float4*)d_out);
}

// Round 6
// 946.224 us; speedup vs baseline: 1.1241x; 1.1241x over previous
//
#include <hip/hip_runtime.h>
#include <stdint.h>

#define NB 65536      // B rows
#define ND 256        // D
#define NK 2048       // K
#define NL 4          // L
#define THRM 0.012f   // accept margin for fp16 screening (score err max ~5e-3)

typedef _Float16 v8h __attribute__((ext_vector_type(8)));   // 8 fp16 (4 VGPR)
typedef __attribute__((ext_vector_type(4))) float v4f;      // MFMA acc
typedef unsigned long long ull;

// ---------------- zero the per-level uncertain counters ----------------
__global__ void k_zero(int* __restrict__ cnt) {
    if (threadIdx.x < NL) cnt[threadIdx.x] = 0;
}

// ---------------- e2: numpy-pairwise sum of emb^2 per row (validated r2) ----------------
// also writes e2n = -0.5*e2 (exact pow2 scale) for MFMA C-init folding
__global__ void k_e2(const float* __restrict__ cb, float* __restrict__ e2,
                     float* __restrict__ e2n) {
    __shared__ float tile[32 * 260];
    const int rowbase = blockIdx.x * 32;
    const float4* cb4 = (const float4*)(cb + (size_t)rowbase * ND);
    for (int it = 0; it < 32; ++it) {
        float4 v = cb4[it * 64 + threadIdx.x];
        *(float4*)&tile[it * 260 + threadIdx.x * 4] = v;
    }
    __syncthreads();
    if (threadIdx.x < 32) {
        const float* a = &tile[threadIdx.x * 260];
        float halves[2];
        for (int h = 0; h < 2; ++h) {
            const float* p = a + h * 128;
            float r8[8];
            #pragma unroll
            for (int j = 0; j < 8; ++j) r8[j] = __fmul_rn(p[j], p[j]);
            for (int i = 8; i < 128; i += 8) {
                #pragma unroll
                for (int j = 0; j < 8; ++j) r8[j] = __fadd_rn(r8[j], __fmul_rn(p[i + j], p[i + j]));
            }
            halves[h] = __fadd_rn(__fadd_rn(__fadd_rn(r8[0], r8[1]), __fadd_rn(r8[2], r8[3])),
                                  __fadd_rn(__fadd_rn(r8[4], r8[5]), __fadd_rn(r8[6], r8[7])));
        }
        const float s = __fadd_rn(halves[0], halves[1]);
        e2[rowbase + threadIdx.x] = s;
        e2n[rowbase + threadIdx.x] = -0.5f * s;
    }
}

// ---------------- convert codebooks to fp16 fragment-major ----------------
__global__ void k_split16(const float* __restrict__ cb, unsigned short* __restrict__ ehf) {
    const int f = blockIdx.x * 256 + threadIdx.x;     // 0 .. L*K*32
    const int g = f & 31;
    const int k = (f >> 5) & (NK - 1);
    const int l = f >> 16;
    const float* p = cb + ((size_t)(l * NK + k) * ND + g * 8);
    float4 a = *(const float4*)p;
    float4 b = *(const float4*)(p + 4);
    v8h h;
    h[0] = (_Float16)a.x; h[1] = (_Float16)a.y; h[2] = (_Float16)a.z; h[3] = (_Float16)a.w;
    h[4] = (_Float16)b.x; h[5] = (_Float16)b.y; h[6] = (_Float16)b.z; h[7] = (_Float16)b.w;
    const size_t u = (size_t)(k >> 4) * 512 + (g >> 2) * 64 + (g & 3) * 16 + (k & 15);
    *(v8h*)(void*)(ehf + (size_t)l * (NK * ND) + u * 8) = h;
}

// ---------------- residual -> fp16 fragment-major (bit-identical to old passA prologue) ----
// layout: resh[fid*8], fid = ((row>>4)*8 + dc)*64 + lane; row=(fid>>9)*16+(lane&15),
//         d = dc*32 + (lane>>4)*8
__global__ __launch_bounds__(256)
void k_res16(const float* __restrict__ residual,
             const float* __restrict__ cb,
             const int* __restrict__ idx_hist,
             unsigned short* __restrict__ resh,
             int level)
{
    const int fid = blockIdx.x * 256 + threadIdx.x;
    const int lane = fid & 63;
    const int dc = (fid >> 6) & 7;
    const int r16 = fid >> 9;
    const int row = r16 * 16 + (lane & 15);
    const int d0 = dc * 32 + (lane >> 4) * 8;
    const float* rp = residual + (size_t)row * ND + d0;
    float buf[8];
    *(float4*)&buf[0] = *(const float4*)rp;
    *(float4*)&buf[4] = *(const float4*)(rp + 4);
    for (int j = 0; j < level; ++j) {
        const int kp = idx_hist[j * NB + row];
        const float* qp = cb + ((size_t)(j * NK + kp) * ND + d0);
        #pragma unroll
        for (int c = 0; c < 8; ++c) buf[c] = __fsub_rn(buf[c], qp[c]);
    }
    v8h h;
    #pragma unroll
    for (int c = 0; c < 8; ++c) h[c] = (_Float16)buf[c];
    *(v8h*)(void*)(resh + (size_t)fid * 8) = h;
}

// async 1KB-per-wave chunk staging: LDS dest is wave-uniform base + lane*16 (linear layout)
__device__ __forceinline__ void stage16k(const char* gbase, char* lbase, int w, int lane) {
    #pragma unroll
    for (int i = 0; i < 4; ++i)
        __builtin_amdgcn_global_load_lds(
            (const __attribute__((address_space(1))) void*)(gbase + i * 4096 + w * 1024 + lane * 16),
            (__attribute__((address_space(3))) void*)(lbase + i * 4096 + w * 1024),
            16, 0, 0);
}

// ---------------- pass A: fp16 MFMA screening, split-K x4, e2 folded into C-init ----------
// tracks MAX of v = dot - 0.5*e2  (score = -2*v); converts at epilogue
// M=64 rows/wave (4x16 sub-tiles): each LDS B-fragment read feeds 4 MFMAs, halving
// LDS-read traffic per output vs M=32 (LDS issue is the R4 bottleneck, 41us/level).
// LDS B-tile staged via global_load_lds (R4 structure; direct-global was latency-bound, R5).
// XCD-aware remap keeps a row-tile's 4 quarter-blocks on one XCD's L2.
__global__ __launch_bounds__(256)
void k_passA(const unsigned short* __restrict__ resh,
             const unsigned short* __restrict__ ehf,   // level slice, fragment-major
             const float* __restrict__ e2n,            // level slice, -0.5*e2
             float* __restrict__ pb1,                  // [4][B] best score
             int* __restrict__ pk1,                    // [4][B] best k
             float* __restrict__ ps2)                  // [4][B] second best
{
    __shared__ unsigned short btile[2][8192];
    __shared__ float e2t[512];

    const int tid = threadIdx.x;
    const int w = tid >> 6;
    const int lane = tid & 63;
    const int kloc = lane & 15;
    const int quad = lane >> 4;

    // remap: xcd = j&7 (HW round-robin), quarter cycles fastest within an XCD
    const int j = blockIdx.x;                  // grid = 1024, 1024%8==0 -> bijective
    const int xcd = j & 7;
    const int within = j >> 3;                 // [0,128)
    const int quarter = within & 3;
    const int rowtile = xcd * 32 + (within >> 2);   // [0,256)
    const int rowbase = rowtile * 256 + w * 64;
    const int r16 = rowbase >> 4;

    const char* src = (const char*)(const void*)(ehf + (size_t)quarter * (512 * ND));

    // prologue: async-stage tiles 0,1 (latency hides under ah/e2t loads below)
    stage16k(src,         (char*)&btile[0][0], w, lane);
    stage16k(src + 16384, (char*)&btile[1][0], w, lane);

    // A fragments: 32 coalesced 16B loads (4 sub-tiles of 16 rows)
    v8h ah[4][8];
    const v8h* rhp = (const v8h*)(const void*)resh;
    #pragma unroll
    for (int m = 0; m < 4; ++m) {
        #pragma unroll
        for (int dc = 0; dc < 8; ++dc)
            ah[m][dc] = rhp[((size_t)(r16 + m) * 8 + dc) * 64 + lane];
    }

    // -0.5*e2 slice for this K-quarter into LDS (broadcast reads, conflict-free)
    e2t[tid] = e2n[quarter * 512 + tid];
    e2t[256 + tid] = e2n[quarter * 512 + 256 + tid];

    float m1[16], m2[16];
    int k1[16];
    #pragma unroll
    for (int s = 0; s < 16; ++s) { m1[s] = -3.0e38f; m2[s] = -3.0e38f; k1[s] = 0; }

    __syncthreads();   // drains vmcnt(0): tiles 0,1 resident

    #pragma unroll 1
    for (int kt = 0; kt < 16; ++kt) {
        const int b = kt & 1;
        #pragma unroll
        for (int nt = 0; nt < 2; ++nt) {
            const int klq = kt * 32 + nt * 16 + kloc;     // k within quarter
            const float e2h = e2t[klq];
            const v4f cinit = {e2h, e2h, e2h, e2h};
            v4f a0, a1, a2, a3;
            {
                const v8h bh = *(const v8h*)(const void*)&btile[b][((nt * 8 + 0) * 64 + quad * 16 + kloc) * 8];
                a0 = __builtin_amdgcn_mfma_f32_16x16x32_f16(ah[0][0], bh, cinit, 0, 0, 0);
                a1 = __builtin_amdgcn_mfma_f32_16x16x32_f16(ah[1][0], bh, cinit, 0, 0, 0);
                a2 = __builtin_amdgcn_mfma_f32_16x16x32_f16(ah[2][0], bh, cinit, 0, 0, 0);
                a3 = __builtin_amdgcn_mfma_f32_16x16x32_f16(ah[3][0], bh, cinit, 0, 0, 0);
            }
            #pragma unroll
            for (int dc = 1; dc < 8; ++dc) {
                const v8h bh = *(const v8h*)(const void*)&btile[b][((nt * 8 + dc) * 64 + quad * 16 + kloc) * 8];
                a0 = __builtin_amdgcn_mfma_f32_16x16x32_f16(ah[0][dc], bh, a0, 0, 0, 0);
                a1 = __builtin_amdgcn_mfma_f32_16x16x32_f16(ah[1][dc], bh, a1, 0, 0, 0);
                a2 = __builtin_amdgcn_mfma_f32_16x16x32_f16(ah[2][dc], bh, a2, 0, 0, 0);
                a3 = __builtin_amdgcn_mfma_f32_16x16x32_f16(ah[3][dc], bh, a3, 0, 0, 0);
            }
            const int kglob = quarter * 512 + klq;
            #pragma unroll
            for (int reg = 0; reg < 4; ++reg) {
                {
                    const float v0 = a0[reg];
                    const bool g = v0 > m1[reg];
                    m2[reg] = __builtin_amdgcn_fmed3f(v0, m1[reg], m2[reg]);
                    m1[reg] = fmaxf(m1[reg], v0);
                    k1[reg] = g ? kglob : k1[reg];
                }
                {
                    const float v1 = a1[reg];
                    const bool g = v1 > m1[4 + reg];
                    m2[4 + reg] = __builtin_amdgcn_fmed3f(v1, m1[4 + reg], m2[4 + reg]);
                    m1[4 + reg] = fmaxf(m1[4 + reg], v1);
                    k1[4 + reg] = g ? kglob : k1[4 + reg];
                }
                {
                    const float v2 = a2[reg];
                    const bool g = v2 > m1[8 + reg];
                    m2[8 + reg] = __builtin_amdgcn_fmed3f(v2, m1[8 + reg], m2[8 + reg]);
                    m1[8 + reg] = fmaxf(m1[8 + reg], v2);
                    k1[8 + reg] = g ? kglob : k1[8 + reg];
                }
                {
                    const float v3 = a3[reg];
                    const bool g = v3 > m1[12 + reg];
                    m2[12 + reg] = __builtin_amdgcn_fmed3f(v3, m1[12 + reg], m2[12 + reg]);
                    m1[12 + reg] = fmaxf(m1[12 + reg], v3);
                    k1[12 + reg] = g ? kglob : k1[12 + reg];
                }
            }
        }
        __syncthreads();   // all waves done reading btile[b]; vmcnt(0) drains tile kt+1
        if (kt + 2 < 16)
            stage16k(src + (size_t)(kt + 2) * 16384, (char*)&btile[b][0], w, lane);
    }

    // 16-lane max-reduction (tie-breaks irrelevant: within-THRM ties go to exact rerank)
    #pragma unroll
    for (int off = 1; off < 16; off <<= 1) {
        #pragma unroll
        for (int s = 0; s < 16; ++s) {
            const float o1 = __shfl_xor(m1[s], off, 16);
            const float o2 = __shfl_xor(m2[s], off, 16);
            const int   ok = __shfl_xor(k1[s], off, 16);
            const float lo = fminf(m1[s], o1);
            m2[s] = fmaxf(fmaxf(m2[s], o2), lo);
            k1[s] = (o1 > m1[s]) ? ok : k1[s];
            m1[s] = fmaxf(m1[s], o1);
        }
    }
    if (kloc == 0) {
        #pragma unroll
        for (int s = 0; s < 16; ++s) {
            const int m = s >> 2, reg = s & 3;
            const int row = rowbase + m * 16 + quad * 4 + reg;
            pb1[(size_t)quarter * NB + row] = -2.0f * m1[s];
            pk1[(size_t)quarter * NB + row] = k1[s];
            ps2[(size_t)quarter * NB + row] = -2.0f * m2[s];
        }
    }
}

// ---------------- merge 4 K-quarters (float compares — scores can be negative!) ----------
__global__ void k_margin(const float* __restrict__ pb1, const int* __restrict__ pk1,
                         const float* __restrict__ ps2,
                         int* __restrict__ idx_l, float* __restrict__ codes,
                         int* __restrict__ ulist, int* __restrict__ cnt, int level)
{
    const int row = blockIdx.x * 256 + threadIdx.x;
    float b1 = pb1[row];
    int   k  = pk1[row];
    float b2 = ps2[row];
    #pragma unroll
    for (int p = 1; p < 4; ++p) {
        const float c1 = pb1[(size_t)p * NB + row];
        const float c2 = ps2[(size_t)p * NB + row];
        const int   ck = pk1[(size_t)p * NB + row];
        if (c1 < b1) { b2 = fminf(b1, c2); b1 = c1; k = ck; }
        else         { b2 = fminf(b2, c1); }
    }
    idx_l[row] = k;
    codes[(size_t)row * NL + level] = (float)k;
    if (b2 - b1 <= THRM) {
        int p = atomicAdd(cnt, 1);
        ulist[p] = row;
    }
}

// ---------------- rerank stage 1: exact scores (bit-exact validated path) ----------------
// emb read direct from L2 (no 64KB LDS stage -> occupancy no longer LDS-capped);
// x2 via 16-lane shfl_xor butterfly reproducing the exact pairwise-sum tree.
__global__ __launch_bounds__(256)
void k_rr1(const float* __restrict__ residual,
           const float* __restrict__ cb,
           const float* __restrict__ emb,
           const float* __restrict__ e2,
           const int* __restrict__ idx_hist,
           const int* __restrict__ ulist,
           const int* __restrict__ cnt,
           ull* __restrict__ partial,
           int level)
{
    __shared__ float resL[16 * 260];
    __shared__ float x2s[16];
    __shared__ int   urows[16];
    __shared__ ull   redM[16][17];

    const int t = threadIdx.x;
    const int ks = blockIdx.x & 31;
    const int rt0 = blockIdx.x >> 5;
    const int n = *cnt;
    const int nrt = (n + 15) >> 4;
    if (rt0 >= nrt) return;

    const int row = t & 15;
    const int kg = t >> 4;
    float e2r[4];
    #pragma unroll
    for (int j = 0; j < 4; ++j) e2r[j] = e2[ks * 64 + kg * 4 + j];
    const float* ep = emb + (size_t)(ks * 64 + kg * 4) * ND;

    for (int rt = rt0; rt < nrt; rt += 64) {
        __syncthreads();
        if (t < 16) {
            const int i = rt * 16 + t;
            urows[t] = ulist[(i < n) ? i : rt * 16];
        }
        __syncthreads();
        #pragma unroll
        for (int i = 0; i < 4; ++i) {
            const int fi = t + 256 * i;
            const int r = fi >> 6, q = fi & 63;
            const int ur = urows[r];
            float4 v = ((const float4*)residual)[(size_t)ur * 64 + q];
            for (int j = 0; j < level; ++j) {
                const int kp = idx_hist[j * NB + ur];
                const float4 qv = ((const float4*)cb)[(size_t)(j * NK + kp) * 64 + q];
                v.x = __fsub_rn(v.x, qv.x);
                v.y = __fsub_rn(v.y, qv.y);
                v.z = __fsub_rn(v.z, qv.z);
                v.w = __fsub_rn(v.w, qv.w);
            }
            *(float4*)&resL[r * 260 + q * 4] = v;
        }
        __syncthreads();
        {
            // 16 lanes per row: lane (h, jj) owns accumulator r8[jj] of half h
            // (identical __fmul_rn/__fadd_rn chain), then xor-butterfly combines in
            // the exact tree order ((01)+(23))+((45)+(67)), then halves[0]+halves[1].
            const int xr = t >> 4;
            const int h = (t >> 3) & 1;
            const int jj = t & 7;
            const float* p = &resL[xr * 260 + h * 128];
            float v = __fmul_rn(p[jj], p[jj]);
            for (int i = 8; i < 128; i += 8)
                v = __fadd_rn(v, __fmul_rn(p[i + jj], p[i + jj]));
            v = __fadd_rn(v, __shfl_xor(v, 1, 16));
            v = __fadd_rn(v, __shfl_xor(v, 2, 16));
            v = __fadd_rn(v, __shfl_xor(v, 4, 16));
            v = __fadd_rn(v, __shfl_xor(v, 8, 16));
            if ((t & 15) == 0) x2s[xr] = v;
        }
        __syncthreads();

        float d0 = 0.f, d1 = 0.f, d2 = 0.f, d3 = 0.f;
        const float* rp = &resL[row * 260];
        #pragma unroll 4
        for (int q = 0; q < 64; ++q) {
            const float4 rv = *(const float4*)&rp[q * 4];
            const float4 e0 = *(const float4*)&ep[q * 4];
            const float4 e1 = *(const float4*)&ep[ND + q * 4];
            const float4 ee2 = *(const float4*)&ep[2 * ND + q * 4];
            const float4 e3 = *(const float4*)&ep[3 * ND + q * 4];
            d0 = __fmaf_rn(rv.x, e0.x, d0); d0 = __fmaf_rn(rv.y, e0.y, d0);
            d0 = __fmaf_rn(rv.z, e0.z, d0); d0 = __fmaf_rn(rv.w, e0.w, d0);
            d1 = __fmaf_rn(rv.x, e1.x, d1); d1 = __fmaf_rn(rv.y, e1.y, d1);
            d1 = __fmaf_rn(rv.z, e1.z, d1); d1 = __fmaf_rn(rv.w, e1.w, d1);
            d2 = __fmaf_rn(rv.x, ee2.x, d2); d2 = __fmaf_rn(rv.y, ee2.y, d2);
            d2 = __fmaf_rn(rv.z, ee2.z, d2); d2 = __fmaf_rn(rv.w, ee2.w, d2);
            d3 = __fmaf_rn(rv.x, e3.x, d3); d3 = __fmaf_rn(rv.y, e3.y, d3);
            d3 = __fmaf_rn(rv.w, e3.w, d3); d3 = __fmaf_rn(rv.z, e3.z, d3);
        }

        const float x2v = x2s[row];
        const int kb = ks * 64 + kg * 4;
        float s;
        ull best, u;
        s = __fsub_rn(__fadd_rn(x2v, e2r[0]), __fmul_rn(2.0f, d0));
        best = ((ull)__float_as_uint(s) << 32) | (ull)(kb + 0);
        s = __fsub_rn(__fadd_rn(x2v, e2r[1]), __fmul_rn(2.0f, d1));
        u = ((ull)__float_as_uint(s) << 32) | (ull)(kb + 1);
        if (u < best) best = u;
        s = __fsub_rn(__fadd_rn(x2v, e2r[2]), __fmul_rn(2.0f, d2));
        u = ((ull)__float_as_uint(s) << 32) | (ull)(kb + 2);
        if (u < best) best = u;
        s = __fsub_rn(__fadd_rn(x2v, e2r[3]), __fmul_rn(2.0f, d3));
        u = ((ull)__float_as_uint(s) << 32) | (ull)(kb + 3);
        if (u < best) best = u;

        redM[row][kg] = best;
        __syncthreads();
        if (t < 16) {
            ull b = redM[t][0];
            #pragma unroll
            for (int g = 1; g < 16; ++g) { const ull v = redM[t][g]; if (v < b) b = v; }
            partial[(size_t)(rt * 16 + t) * 32 + ks] = b;
        }
    }
}

// ---------------- rerank stage 2: reduce 32 k-slices per uncertain row ----------------
__global__ void k_rr2(const ull* __restrict__ partial,
                      const int* __restrict__ ulist,
                      const int* __restrict__ cnt,
                      int* __restrict__ idx_l,
                      float* __restrict__ codes,
                      int level)
{
    const int n = *cnt;
    for (int i = blockIdx.x * 256 + threadIdx.x; i < n; i += gridDim.x * 256) {
        const ull* p = &partial[(size_t)i * 32];
        ull b = p[0];
        #pragma unroll
        for (int s2 = 1; s2 < 32; ++s2) { const ull v = p[s2]; if (v < b) b = v; }
        const int k = (int)(b & 0xffffffffull);
        const int row = ulist[i];
        idx_l[row] = k;
        codes[(size_t)row * NL + level] = (float)k;
    }
}

// ---------------- finalize: quantized = fadd chain q0+q1+q2+q3 (reference order) ----------------
__global__ void k_finalize(const float* __restrict__ cb, const int* __restrict__ idx_hist,
                           float4* __restrict__ outq) {
    const int i = blockIdx.x * 256 + threadIdx.x;
    const int r = i >> 6, c = i & 63;
    const float4* cb4 = (const float4*)cb;
    const int i0 = idx_hist[r];
    const int i1 = idx_hist[NB + r];
    const int i2 = idx_hist[2 * NB + r];
    const int i3 = idx_hist[3 * NB + r];
    float4 q = cb4[(size_t)i0 * 64 + c];
    float4 t1 = cb4[(size_t)(NK + i1) * 64 + c];
    q.x = __fadd_rn(q.x, t1.x); q.y = __fadd_rn(q.y, t1.y);
    q.z = __fadd_rn(q.z, t1.z); q.w = __fadd_rn(q.w, t1.w);
    float4 t2 = cb4[(size_t)(2 * NK + i2) * 64 + c];
    q.x = __fadd_rn(q.x, t2.x); q.y = __fadd_rn(q.y, t2.y);
    q.z = __fadd_rn(q.z, t2.z); q.w = __fadd_rn(q.w, t2.w);
    float4 t3 = cb4[(size_t)(3 * NK + i3) * 64 + c];
    q.x = __fadd_rn(q.x, t3.x); q.y = __fadd_rn(q.y, t3.y);
    q.z = __fadd_rn(q.z, t3.z); q.w = __fadd_rn(q.w, t3.w);
    outq[i] = q;
}

extern "C" void kernel_launch(void* const* d_in, const int* in_sizes, int n_in,
                              void* d_out, int out_size, void* d_ws, size_t ws_size,
                              hipStream_t stream) {
    const float* residual = (const float*)d_in[0];
    const float* cb = (const float*)d_in[1];

    float* pb1 = (float*)d_ws;                                   // [4][B] 1 MB
    int* pk1 = (int*)(pb1 + 4 * (size_t)NB);                     // [4][B] 1 MB
    float* ps2 = (float*)(pk1 + 4 * (size_t)NB);                 // [4][B] 1 MB
    ull* partial = (ull*)(ps2 + 4 * (size_t)NB);                 // 16.8 MB
    float* e2 = (float*)(partial + (size_t)(NB + 16) * 32);      // 32 KB
    float* e2n = e2 + (size_t)NL * NK;                           // 32 KB
    int* idx_hist = (int*)(e2n + (size_t)NL * NK);               // [L][B] 1 MB
    int* ulist = idx_hist + (size_t)NL * NB;                     // 256 KB
    int* cnt = ulist + NB;
    unsigned short* ehf = (unsigned short*)(cnt + 64);           // fp16 frag-major 4 MB
    unsigned short* resh = ehf + (size_t)NL * NK * ND;           // fp16 residual frags 32 MB

    float* codes = (float*)d_out + (size_t)NB * ND;              // fp32 [B, L]

    k_zero<<<1, 64, 0, stream>>>(cnt);
    k_e2<<<NL * NK / 32, 64, 0, stream>>>(cb, e2, e2n);
    k_split16<<<NL * NK * 32 / 256, 256, 0, stream>>>(cb, ehf);

    for (int l = 0; l < NL; ++l) {
        const unsigned short* ehl = ehf + (size_t)l * NK * ND;
        const float* e2l = e2 + (size_t)l * NK;
        const float* e2nl = e2n + (size_t)l * NK;
        int* idx_l = idx_hist + (size_t)l * NB;
        k_res16<<<NB * ND / 8 / 256, 256, 0, stream>>>(residual, cb, idx_hist, resh, l);
        k_passA<<<NB / 256 * 4, 256, 0, stream>>>(resh, ehl, e2nl, pb1, pk1, ps2);
        k_margin<<<NB / 256, 256, 0, stream>>>(pb1, pk1, ps2, idx_l, codes, ulist, cnt + l, l);
        k_rr1<<<2048, 256, 0, stream>>>(residual, cb, cb + (size_t)l * NK * ND, e2l,
                                        idx_hist, ulist, cnt + l, partial, l);
        k_rr2<<<64, 256, 0, stream>>>(partial, ulist, cnt + l, idx_l, codes, l);
    }
    k_finalize<<<NB * ND / 4 / 256, 256, 0, stream>>>(cb, idx_hist, (float4*)d_out);
}

// Round 7
// 880.244 us; speedup vs baseline: 1.2083x; 1.0750x over previous
//
#include <hip/hip_runtime.h>
#include <stdint.h>

#define NB 65536      // B rows
#define ND 256        // D
#define NK 2048       // K
#define NL 4          // L
#define THRM 0.012f   // accept margin for fp16 screening (score err max ~5e-3)

typedef _Float16 v8h __attribute__((ext_vector_type(8)));   // 8 fp16 (4 VGPR)
typedef __attribute__((ext_vector_type(4))) float v4f;      // MFMA acc
typedef unsigned long long ull;

// ---------------- zero the per-level uncertain counters ----------------
__global__ void k_zero(int* __restrict__ cnt) {
    if (threadIdx.x < NL) cnt[threadIdx.x] = 0;
}

// ---------------- e2: numpy-pairwise sum of emb^2 per row (validated r2) ----------------
// also writes e2n = -0.5*e2 (exact pow2 scale) for MFMA C-init folding
__global__ void k_e2(const float* __restrict__ cb, float* __restrict__ e2,
                     float* __restrict__ e2n) {
    __shared__ float tile[32 * 260];
    const int rowbase = blockIdx.x * 32;
    const float4* cb4 = (const float4*)(cb + (size_t)rowbase * ND);
    for (int it = 0; it < 32; ++it) {
        float4 v = cb4[it * 64 + threadIdx.x];
        *(float4*)&tile[it * 260 + threadIdx.x * 4] = v;
    }
    __syncthreads();
    if (threadIdx.x < 32) {
        const float* a = &tile[threadIdx.x * 260];
        float halves[2];
        for (int h = 0; h < 2; ++h) {
            const float* p = a + h * 128;
            float r8[8];
            #pragma unroll
            for (int j = 0; j < 8; ++j) r8[j] = __fmul_rn(p[j], p[j]);
            for (int i = 8; i < 128; i += 8) {
                #pragma unroll
                for (int j = 0; j < 8; ++j) r8[j] = __fadd_rn(r8[j], __fmul_rn(p[i + j], p[i + j]));
            }
            halves[h] = __fadd_rn(__fadd_rn(__fadd_rn(r8[0], r8[1]), __fadd_rn(r8[2], r8[3])),
                                  __fadd_rn(__fadd_rn(r8[4], r8[5]), __fadd_rn(r8[6], r8[7])));
        }
        const float s = __fadd_rn(halves[0], halves[1]);
        e2[rowbase + threadIdx.x] = s;
        e2n[rowbase + threadIdx.x] = -0.5f * s;
    }
}

// ---------------- convert codebooks to fp16 fragment-major ----------------
__global__ void k_split16(const float* __restrict__ cb, unsigned short* __restrict__ ehf) {
    const int f = blockIdx.x * 256 + threadIdx.x;     // 0 .. L*K*32
    const int g = f & 31;
    const int k = (f >> 5) & (NK - 1);
    const int l = f >> 16;
    const float* p = cb + ((size_t)(l * NK + k) * ND + g * 8);
    float4 a = *(const float4*)p;
    float4 b = *(const float4*)(p + 4);
    v8h h;
    h[0] = (_Float16)a.x; h[1] = (_Float16)a.y; h[2] = (_Float16)a.z; h[3] = (_Float16)a.w;
    h[4] = (_Float16)b.x; h[5] = (_Float16)b.y; h[6] = (_Float16)b.z; h[7] = (_Float16)b.w;
    const size_t u = (size_t)(k >> 4) * 512 + (g >> 2) * 64 + (g & 3) * 16 + (k & 15);
    *(v8h*)(void*)(ehf + (size_t)l * (NK * ND) + u * 8) = h;
}

// ---------------- residual -> fp16 fragment-major (bit-identical to old passA prologue) ----
// layout: resh[fid*8], fid = ((row>>4)*8 + dc)*64 + lane; row=(fid>>9)*16+(lane&15),
//         d = dc*32 + (lane>>4)*8
__global__ __launch_bounds__(256)
void k_res16(const float* __restrict__ residual,
             const float* __restrict__ cb,
             const int* __restrict__ idx_hist,
             unsigned short* __restrict__ resh,
             int level)
{
    const int fid = blockIdx.x * 256 + threadIdx.x;
    const int lane = fid & 63;
    const int dc = (fid >> 6) & 7;
    const int r16 = fid >> 9;
    const int row = r16 * 16 + (lane & 15);
    const int d0 = dc * 32 + (lane >> 4) * 8;
    const float* rp = residual + (size_t)row * ND + d0;
    float buf[8];
    *(float4*)&buf[0] = *(const float4*)rp;
    *(float4*)&buf[4] = *(const float4*)(rp + 4);
    for (int j = 0; j < level; ++j) {
        const int kp = idx_hist[j * NB + row];
        const float* qp = cb + ((size_t)(j * NK + kp) * ND + d0);
        #pragma unroll
        for (int c = 0; c < 8; ++c) buf[c] = __fsub_rn(buf[c], qp[c]);
    }
    v8h h;
    #pragma unroll
    for (int c = 0; c < 8; ++c) h[c] = (_Float16)buf[c];
    *(v8h*)(void*)(resh + (size_t)fid * 8) = h;
}

// async 8KB-per-block stage: 2KB per wave, LDS dest wave-uniform base + lane*16 (linear)
__device__ __forceinline__ void stage8k(const char* gbase, char* lbase, int w, int lane) {
    #pragma unroll
    for (int i = 0; i < 2; ++i)
        __builtin_amdgcn_global_load_lds(
            (const __attribute__((address_space(1))) void*)(gbase + i * 4096 + w * 1024 + lane * 16),
            (__attribute__((address_space(3))) void*)(lbase + i * 4096 + w * 1024),
            16, 0, 0);
}

// ---------------- pass A: fp16 MFMA screening, split-K x4, e2 folded into C-init ----------
// tracks MAX of v = dot - 0.5*e2  (score = -2*v); converts at epilogue
// R4 structure (M=32/wave, 84 VGPR) but 8KB stage quantum (one 16-k group per stage):
// LDS 34.8KB -> ~18.5KB so ~6 blocks/CU co-resident (vs 2.3) -- cross-block overlap of
// LDS-issue / MFMA / VALU phases is what closes the gap to the ~34us/level floor.
// XCD-aware remap keeps a row-tile's 4 quarter-blocks on one XCD's L2.
__global__ __launch_bounds__(256)
void k_passA(const unsigned short* __restrict__ resh,
             const unsigned short* __restrict__ ehf,   // level slice, fragment-major
             const float* __restrict__ e2n,            // level slice, -0.5*e2
             float* __restrict__ pb1,                  // [4][B] best score
             int* __restrict__ pk1,                    // [4][B] best k
             float* __restrict__ ps2)                  // [4][B] second best
{
    __shared__ unsigned short btile[2][4096];   // 2 x 8KB
    __shared__ float e2t[512];

    const int tid = threadIdx.x;
    const int w = tid >> 6;
    const int lane = tid & 63;
    const int kloc = lane & 15;
    const int quad = lane >> 4;

    // remap: xcd = j&7 (HW round-robin), quarter cycles fastest within an XCD
    const int j = blockIdx.x;                  // grid = 2048, 2048%8==0 -> bijective
    const int xcd = j & 7;
    const int within = j >> 3;                 // [0,256)
    const int quarter = within & 3;
    const int rowtile = xcd * 64 + (within >> 2);   // [0,512)
    const int rowbase = rowtile * 128 + w * 32;
    const int r16 = rowbase >> 4;

    const char* src = (const char*)(const void*)(ehf + (size_t)quarter * (512 * ND));

    // prologue: async-stage k-groups 0,1 (latency hides under ah/e2t loads below)
    stage8k(src,        (char*)&btile[0][0], w, lane);
    stage8k(src + 8192, (char*)&btile[1][0], w, lane);

    // A fragments: 16 coalesced 16B loads (prologue hoisted into k_res16)
    v8h ah[2][8];
    const v8h* rhp = (const v8h*)(const void*)resh;
    #pragma unroll
    for (int m = 0; m < 2; ++m) {
        #pragma unroll
        for (int dc = 0; dc < 8; ++dc)
            ah[m][dc] = rhp[((size_t)(r16 + m) * 8 + dc) * 64 + lane];
    }

    // -0.5*e2 slice for this K-quarter into LDS (broadcast reads, conflict-free)
    e2t[tid] = e2n[quarter * 512 + tid];
    e2t[256 + tid] = e2n[quarter * 512 + 256 + tid];

    float m1[8], m2[8];
    int k1[8];
    #pragma unroll
    for (int s = 0; s < 8; ++s) { m1[s] = -3.0e38f; m2[s] = -3.0e38f; k1[s] = 0; }

    __syncthreads();   // drains vmcnt(0): k-groups 0,1 resident

    #pragma unroll 1
    for (int st = 0; st < 32; ++st) {
        const int b = st & 1;
        const int klq = st * 16 + kloc;               // k within quarter
        const float e2h = e2t[klq];
        const v4f cinit = {e2h, e2h, e2h, e2h};
        v4f a0a, a1a;
        v4f a0b = {0.f, 0.f, 0.f, 0.f}, a1b = {0.f, 0.f, 0.f, 0.f};
        {
            const v8h bh = *(const v8h*)(const void*)&btile[b][((0) * 64 + quad * 16 + kloc) * 8];
            a0a = __builtin_amdgcn_mfma_f32_16x16x32_f16(ah[0][0], bh, cinit, 0, 0, 0);
            a1a = __builtin_amdgcn_mfma_f32_16x16x32_f16(ah[1][0], bh, cinit, 0, 0, 0);
        }
        #pragma unroll
        for (int dc = 1; dc < 4; ++dc) {
            const v8h bh = *(const v8h*)(const void*)&btile[b][((dc) * 64 + quad * 16 + kloc) * 8];
            a0a = __builtin_amdgcn_mfma_f32_16x16x32_f16(ah[0][dc], bh, a0a, 0, 0, 0);
            a1a = __builtin_amdgcn_mfma_f32_16x16x32_f16(ah[1][dc], bh, a1a, 0, 0, 0);
        }
        #pragma unroll
        for (int dc = 4; dc < 8; ++dc) {
            const v8h bh = *(const v8h*)(const void*)&btile[b][((dc) * 64 + quad * 16 + kloc) * 8];
            a0b = __builtin_amdgcn_mfma_f32_16x16x32_f16(ah[0][dc], bh, a0b, 0, 0, 0);
            a1b = __builtin_amdgcn_mfma_f32_16x16x32_f16(ah[1][dc], bh, a1b, 0, 0, 0);
        }
        const int kglob = quarter * 512 + klq;
        #pragma unroll
        for (int reg = 0; reg < 4; ++reg) {
            const float v0 = a0a[reg] + a0b[reg];
            const bool g0 = v0 > m1[reg];
            m2[reg] = __builtin_amdgcn_fmed3f(v0, m1[reg], m2[reg]);  // = max(m2, min(m1, v0))
            m1[reg] = fmaxf(m1[reg], v0);
            k1[reg] = g0 ? kglob : k1[reg];
            const float v1 = a1a[reg] + a1b[reg];
            const bool g1 = v1 > m1[4 + reg];
            m2[4 + reg] = __builtin_amdgcn_fmed3f(v1, m1[4 + reg], m2[4 + reg]);
            m1[4 + reg] = fmaxf(m1[4 + reg], v1);
            k1[4 + reg] = g1 ? kglob : k1[4 + reg];
        }
        __syncthreads();   // all waves done reading btile[b]; vmcnt(0) drains group st+1
        if (st + 2 < 32)
            stage8k(src + (size_t)(st + 2) * 8192, (char*)&btile[b][0], w, lane);
    }

    // 16-lane max-reduction (tie-breaks irrelevant: within-THRM ties go to exact rerank)
    #pragma unroll
    for (int off = 1; off < 16; off <<= 1) {
        #pragma unroll
        for (int s = 0; s < 8; ++s) {
            const float o1 = __shfl_xor(m1[s], off, 16);
            const float o2 = __shfl_xor(m2[s], off, 16);
            const int   ok = __shfl_xor(k1[s], off, 16);
            const float lo = fminf(m1[s], o1);
            m2[s] = fmaxf(fmaxf(m2[s], o2), lo);
            k1[s] = (o1 > m1[s]) ? ok : k1[s];
            m1[s] = fmaxf(m1[s], o1);
        }
    }
    if (kloc == 0) {
        #pragma unroll
        for (int s = 0; s < 8; ++s) {
            const int m = s >> 2, reg = s & 3;
            const int row = rowbase + m * 16 + quad * 4 + reg;
            pb1[(size_t)quarter * NB + row] = -2.0f * m1[s];
            pk1[(size_t)quarter * NB + row] = k1[s];
            ps2[(size_t)quarter * NB + row] = -2.0f * m2[s];
        }
    }
}

// ---------------- merge 4 K-quarters (float compares — scores can be negative!) ----------
__global__ void k_margin(const float* __restrict__ pb1, const int* __restrict__ pk1,
                         const float* __restrict__ ps2,
                         int* __restrict__ idx_l, float* __restrict__ codes,
                         int* __restrict__ ulist, int* __restrict__ cnt, int level)
{
    const int row = blockIdx.x * 256 + threadIdx.x;
    float b1 = pb1[row];
    int   k  = pk1[row];
    float b2 = ps2[row];
    #pragma unroll
    for (int p = 1; p < 4; ++p) {
        const float c1 = pb1[(size_t)p * NB + row];
        const float c2 = ps2[(size_t)p * NB + row];
        const int   ck = pk1[(size_t)p * NB + row];
        if (c1 < b1) { b2 = fminf(b1, c2); b1 = c1; k = ck; }
        else         { b2 = fminf(b2, c1); }
    }
    idx_l[row] = k;
    codes[(size_t)row * NL + level] = (float)k;
    if (b2 - b1 <= THRM) {
        int p = atomicAdd(cnt, 1);
        ulist[p] = row;
    }
}

// ---------------- rerank stage 1: exact scores (bit-exact validated path) ----------------
// emb read direct from L2 (no 64KB LDS stage -> occupancy no longer LDS-capped);
// x2 via 16-lane shfl_xor butterfly reproducing the exact pairwise-sum tree.
__global__ __launch_bounds__(256)
void k_rr1(const float* __restrict__ residual,
           const float* __restrict__ cb,
           const float* __restrict__ emb,
           const float* __restrict__ e2,
           const int* __restrict__ idx_hist,
           const int* __restrict__ ulist,
           const int* __restrict__ cnt,
           ull* __restrict__ partial,
           int level)
{
    __shared__ float resL[16 * 260];
    __shared__ float x2s[16];
    __shared__ int   urows[16];
    __shared__ ull   redM[16][17];

    const int t = threadIdx.x;
    const int ks = blockIdx.x & 31;
    const int rt0 = blockIdx.x >> 5;
    const int n = *cnt;
    const int nrt = (n + 15) >> 4;
    if (rt0 >= nrt) return;

    const int row = t & 15;
    const int kg = t >> 4;
    float e2r[4];
    #pragma unroll
    for (int j = 0; j < 4; ++j) e2r[j] = e2[ks * 64 + kg * 4 + j];
    const float* ep = emb + (size_t)(ks * 64 + kg * 4) * ND;

    for (int rt = rt0; rt < nrt; rt += 64) {
        __syncthreads();
        if (t < 16) {
            const int i = rt * 16 + t;
            urows[t] = ulist[(i < n) ? i : rt * 16];
        }
        __syncthreads();
        #pragma unroll
        for (int i = 0; i < 4; ++i) {
            const int fi = t + 256 * i;
            const int r = fi >> 6, q = fi & 63;
            const int ur = urows[r];
            float4 v = ((const float4*)residual)[(size_t)ur * 64 + q];
            for (int j = 0; j < level; ++j) {
                const int kp = idx_hist[j * NB + ur];
                const float4 qv = ((const float4*)cb)[(size_t)(j * NK + kp) * 64 + q];
                v.x = __fsub_rn(v.x, qv.x);
                v.y = __fsub_rn(v.y, qv.y);
                v.z = __fsub_rn(v.z, qv.z);
                v.w = __fsub_rn(v.w, qv.w);
            }
            *(float4*)&resL[r * 260 + q * 4] = v;
        }
        __syncthreads();
        {
            // 16 lanes per row: lane (h, jj) owns accumulator r8[jj] of half h
            // (identical __fmul_rn/__fadd_rn chain), then xor-butterfly combines in
            // the exact tree order ((01)+(23))+((45)+(67)), then halves[0]+halves[1].
            const int xr = t >> 4;
            const int h = (t >> 3) & 1;
            const int jj = t & 7;
            const float* p = &resL[xr * 260 + h * 128];
            float v = __fmul_rn(p[jj], p[jj]);
            for (int i = 8; i < 128; i += 8)
                v = __fadd_rn(v, __fmul_rn(p[i + jj], p[i + jj]));
            v = __fadd_rn(v, __shfl_xor(v, 1, 16));
            v = __fadd_rn(v, __shfl_xor(v, 2, 16));
            v = __fadd_rn(v, __shfl_xor(v, 4, 16));
            v = __fadd_rn(v, __shfl_xor(v, 8, 16));
            if ((t & 15) == 0) x2s[xr] = v;
        }
        __syncthreads();

        float d0 = 0.f, d1 = 0.f, d2 = 0.f, d3 = 0.f;
        const float* rp = &resL[row * 260];
        #pragma unroll 4
        for (int q = 0; q < 64; ++q) {
            const float4 rv = *(const float4*)&rp[q * 4];
            const float4 e0 = *(const float4*)&ep[q * 4];
            const float4 e1 = *(const float4*)&ep[ND + q * 4];
            const float4 ee2 = *(const float4*)&ep[2 * ND + q * 4];
            const float4 e3 = *(const float4*)&ep[3 * ND + q * 4];
            d0 = __fmaf_rn(rv.x, e0.x, d0); d0 = __fmaf_rn(rv.y, e0.y, d0);
            d0 = __fmaf_rn(rv.z, e0.z, d0); d0 = __fmaf_rn(rv.w, e0.w, d0);
            d1 = __fmaf_rn(rv.x, e1.x, d1); d1 = __fmaf_rn(rv.y, e1.y, d1);
            d1 = __fmaf_rn(rv.z, e1.z, d1); d1 = __fmaf_rn(rv.w, e1.w, d1);
            d2 = __fmaf_rn(rv.x, ee2.x, d2); d2 = __fmaf_rn(rv.y, ee2.y, d2);
            d2 = __fmaf_rn(rv.z, ee2.z, d2); d2 = __fmaf_rn(rv.w, ee2.w, d2);
            d3 = __fmaf_rn(rv.x, e3.x, d3); d3 = __fmaf_rn(rv.y, e3.y, d3);
            d3 = __fmaf_rn(rv.z, e3.z, d3); d3 = __fmaf_rn(rv.w, e3.w, d3);
        }

        const float x2v = x2s[row];
        const int kb = ks * 64 + kg * 4;
        float s;
        ull best, u;
        s = __fsub_rn(__fadd_rn(x2v, e2r[0]), __fmul_rn(2.0f, d0));
        best = ((ull)__float_as_uint(s) << 32) | (ull)(kb + 0);
        s = __fsub_rn(__fadd_rn(x2v, e2r[1]), __fmul_rn(2.0f, d1));
        u = ((ull)__float_as_uint(s) << 32) | (ull)(kb + 1);
        if (u < best) best = u;
        s = __fsub_rn(__fadd_rn(x2v, e2r[2]), __fmul_rn(2.0f, d2));
        u = ((ull)__float_as_uint(s) << 32) | (ull)(kb + 2);
        if (u < best) best = u;
        s = __fsub_rn(__fadd_rn(x2v, e2r[3]), __fmul_rn(2.0f, d3));
        u = ((ull)__float_as_uint(s) << 32) | (ull)(kb + 3);
        if (u < best) best = u;

        redM[row][kg] = best;
        __syncthreads();
        if (t < 16) {
            ull b = redM[t][0];
            #pragma unroll
            for (int g = 1; g < 16; ++g) { const ull v = redM[t][g]; if (v < b) b = v; }
            partial[(size_t)(rt * 16 + t) * 32 + ks] = b;
        }
    }
}

// ---------------- rerank stage 2: reduce 32 k-slices per uncertain row ----------------
__global__ void k_rr2(const ull* __restrict__ partial,
                      const int* __restrict__ ulist,
                      const int* __restrict__ cnt,
                      int* __restrict__ idx_l,
                      float* __restrict__ codes,
                      int level)
{
    const int n = *cnt;
    for (int i = blockIdx.x * 256 + threadIdx.x; i < n; i += gridDim.x * 256) {
        const ull* p = &partial[(size_t)i * 32];
        ull b = p[0];
        #pragma unroll
        for (int s2 = 1; s2 < 32; ++s2) { const ull v = p[s2]; if (v < b) b = v; }
        const int k = (int)(b & 0xffffffffull);
        const int row = ulist[i];
        idx_l[row] = k;
        codes[(size_t)row * NL + level] = (float)k;
    }
}

// ---------------- finalize: quantized = fadd chain q0+q1+q2+q3 (reference order) ----------------
__global__ void k_finalize(const float* __restrict__ cb, const int* __restrict__ idx_hist,
                           float4* __restrict__ outq) {
    const int i = blockIdx.x * 256 + threadIdx.x;
    const int r = i >> 6, c = i & 63;
    const float4* cb4 = (const float4*)cb;
    const int i0 = idx_hist[r];
    const int i1 = idx_hist[NB + r];
    const int i2 = idx_hist[2 * NB + r];
    const int i3 = idx_hist[3 * NB + r];
    float4 q = cb4[(size_t)i0 * 64 + c];
    float4 t1 = cb4[(size_t)(NK + i1) * 64 + c];
    q.x = __fadd_rn(q.x, t1.x); q.y = __fadd_rn(q.y, t1.y);
    q.z = __fadd_rn(q.z, t1.z); q.w = __fadd_rn(q.w, t1.w);
    float4 t2 = cb4[(size_t)(2 * NK + i2) * 64 + c];
    q.x = __fadd_rn(q.x, t2.x); q.y = __fadd_rn(q.y, t2.y);
    q.z = __fadd_rn(q.z, t2.z); q.w = __fadd_rn(q.w, t2.w);
    float4 t3 = cb4[(size_t)(3 * NK + i3) * 64 + c];
    q.x = __fadd_rn(q.x, t3.x); q.y = __fadd_rn(q.y, t3.y);
    q.z = __fadd_rn(q.z, t3.z); q.w = __fadd_rn(q.w, t3.w);
    outq[i] = q;
}

extern "C" void kernel_launch(void* const* d_in, const int* in_sizes, int n_in,
                              void* d_out, int out_size, void* d_ws, size_t ws_size,
                              hipStream_t stream) {
    const float* residual = (const float*)d_in[0];
    const float* cb = (const float*)d_in[1];

    float* pb1 = (float*)d_ws;                                   // [4][B] 1 MB
    int* pk1 = (int*)(pb1 + 4 * (size_t)NB);                     // [4][B] 1 MB
    float* ps2 = (float*)(pk1 + 4 * (size_t)NB);                 // [4][B] 1 MB
    ull* partial = (ull*)(ps2 + 4 * (size_t)NB);                 // 16.8 MB
    float* e2 = (float*)(partial + (size_t)(NB + 16) * 32);      // 32 KB
    float* e2n = e2 + (size_t)NL * NK;                           // 32 KB
    int* idx_hist = (int*)(e2n + (size_t)NL * NK);               // [L][B] 1 MB
    int* ulist = idx_hist + (size_t)NL * NB;                     // 256 KB
    int* cnt = ulist + NB;
    unsigned short* ehf = (unsigned short*)(cnt + 64);           // fp16 frag-major 4 MB
    unsigned short* resh = ehf + (size_t)NL * NK * ND;           // fp16 residual frags 32 MB

    float* codes = (float*)d_out + (size_t)NB * ND;              // fp32 [B, L]

    k_zero<<<1, 64, 0, stream>>>(cnt);
    k_e2<<<NL * NK / 32, 64, 0, stream>>>(cb, e2, e2n);
    k_split16<<<NL * NK * 32 / 256, 256, 0, stream>>>(cb, ehf);

    for (int l = 0; l < NL; ++l) {
        const unsigned short* ehl = ehf + (size_t)l * NK * ND;
        const float* e2l = e2 + (size_t)l * NK;
        const float* e2nl = e2n + (size_t)l * NK;
        int* idx_l = idx_hist + (size_t)l * NB;
        k_res16<<<NB * ND / 8 / 256, 256, 0, stream>>>(residual, cb, idx_hist, resh, l);
        k_passA<<<NB / 128 * 4, 256, 0, stream>>>(resh, ehl, e2nl, pb1, pk1, ps2);
        k_margin<<<NB / 256, 256, 0, stream>>>(pb1, pk1, ps2, idx_l, codes, ulist, cnt + l, l);
        k_rr1<<<2048, 256, 0, stream>>>(residual, cb, cb + (size_t)l * NK * ND, e2l,
                                        idx_hist, ulist, cnt + l, partial, l);
        k_rr2<<<64, 256, 0, stream>>>(partial, ulist, cnt + l, idx_l, codes, l);
    }
    k_finalize<<<NB * ND / 4 / 256, 256, 0, stream>>>(cb, idx_hist, (float4*)d_out);
}

// Round 8
// 854.484 us; speedup vs baseline: 1.2448x; 1.0301x over previous
//
#include <hip/hip_runtime.h>
#include <stdint.h>

#define NB 65536      // B rows
#define ND 256        // D
#define NK 2048       // K
#define NL 4          // L
#define THRM 0.012f   // accept margin for fp16 screening (score err max ~5e-3)

typedef _Float16 v8h __attribute__((ext_vector_type(8)));   // 8 fp16 (4 VGPR)
typedef __attribute__((ext_vector_type(4))) float v4f;      // MFMA acc
typedef unsigned long long ull;

// ---------------- zero the per-level uncertain counters ----------------
__global__ void k_zero(int* __restrict__ cnt) {
    if (threadIdx.x < NL) cnt[threadIdx.x] = 0;
}

// ---------------- e2: numpy-pairwise sum of emb^2 per row (validated r2) ----------------
// also writes e2n = -0.5*e2 (exact pow2 scale) for MFMA C-init folding
__global__ void k_e2(const float* __restrict__ cb, float* __restrict__ e2,
                     float* __restrict__ e2n) {
    __shared__ float tile[32 * 260];
    const int rowbase = blockIdx.x * 32;
    const float4* cb4 = (const float4*)(cb + (size_t)rowbase * ND);
    for (int it = 0; it < 32; ++it) {
        float4 v = cb4[it * 64 + threadIdx.x];
        *(float4*)&tile[it * 260 + threadIdx.x * 4] = v;
    }
    __syncthreads();
    if (threadIdx.x < 32) {
        const float* a = &tile[threadIdx.x * 260];
        float halves[2];
        for (int h = 0; h < 2; ++h) {
            const float* p = a + h * 128;
            float r8[8];
            #pragma unroll
            for (int j = 0; j < 8; ++j) r8[j] = __fmul_rn(p[j], p[j]);
            for (int i = 8; i < 128; i += 8) {
                #pragma unroll
                for (int j = 0; j < 8; ++j) r8[j] = __fadd_rn(r8[j], __fmul_rn(p[i + j], p[i + j]));
            }
            halves[h] = __fadd_rn(__fadd_rn(__fadd_rn(r8[0], r8[1]), __fadd_rn(r8[2], r8[3])),
                                  __fadd_rn(__fadd_rn(r8[4], r8[5]), __fadd_rn(r8[6], r8[7])));
        }
        const float s = __fadd_rn(halves[0], halves[1]);
        e2[rowbase + threadIdx.x] = s;
        e2n[rowbase + threadIdx.x] = -0.5f * s;
    }
}

// ---------------- convert codebooks to fp16 fragment-major ----------------
__global__ void k_split16(const float* __restrict__ cb, unsigned short* __restrict__ ehf) {
    const int f = blockIdx.x * 256 + threadIdx.x;     // 0 .. L*K*32
    const int g = f & 31;
    const int k = (f >> 5) & (NK - 1);
    const int l = f >> 16;
    const float* p = cb + ((size_t)(l * NK + k) * ND + g * 8);
    float4 a = *(const float4*)p;
    float4 b = *(const float4*)(p + 4);
    v8h h;
    h[0] = (_Float16)a.x; h[1] = (_Float16)a.y; h[2] = (_Float16)a.z; h[3] = (_Float16)a.w;
    h[4] = (_Float16)b.x; h[5] = (_Float16)b.y; h[6] = (_Float16)b.z; h[7] = (_Float16)b.w;
    const size_t u = (size_t)(k >> 4) * 512 + (g >> 2) * 64 + (g & 3) * 16 + (k & 15);
    *(v8h*)(void*)(ehf + (size_t)l * (NK * ND) + u * 8) = h;
}

// ---------------- residual -> fp16 fragment-major (bit-identical to old passA prologue) ----
// layout: resh[fid*8], fid = ((row>>4)*8 + dc)*64 + lane; row=(fid>>9)*16+(lane&15),
//         d = dc*32 + (lane>>4)*8
__global__ __launch_bounds__(256)
void k_res16(const float* __restrict__ residual,
             const float* __restrict__ cb,
             const int* __restrict__ idx_hist,
             unsigned short* __restrict__ resh,
             int level)
{
    const int fid = blockIdx.x * 256 + threadIdx.x;
    const int lane = fid & 63;
    const int dc = (fid >> 6) & 7;
    const int r16 = fid >> 9;
    const int row = r16 * 16 + (lane & 15);
    const int d0 = dc * 32 + (lane >> 4) * 8;
    const float* rp = residual + (size_t)row * ND + d0;
    float buf[8];
    *(float4*)&buf[0] = *(const float4*)rp;
    *(float4*)&buf[4] = *(const float4*)(rp + 4);
    for (int j = 0; j < level; ++j) {
        const int kp = idx_hist[j * NB + row];
        const float* qp = cb + ((size_t)(j * NK + kp) * ND + d0);
        #pragma unroll
        for (int c = 0; c < 8; ++c) buf[c] = __fsub_rn(buf[c], qp[c]);
    }
    v8h h;
    #pragma unroll
    for (int c = 0; c < 8; ++c) h[c] = (_Float16)buf[c];
    *(v8h*)(void*)(resh + (size_t)fid * 8) = h;
}

// async 1KB-per-wave chunk staging: LDS dest is wave-uniform base + lane*16 (linear layout)
__device__ __forceinline__ void stage16k(const char* gbase, char* lbase, int w, int lane) {
    #pragma unroll
    for (int i = 0; i < 4; ++i)
        __builtin_amdgcn_global_load_lds(
            (const __attribute__((address_space(1))) void*)(gbase + i * 4096 + w * 1024 + lane * 16),
            (__attribute__((address_space(3))) void*)(lbase + i * 4096 + w * 1024),
            16, 0, 0);
}

// ---------------- pass A: fp16 MFMA screening, split-K x4, e2 folded into C-init ----------
// tracks MAX of v = dot - 0.5*e2  (score = -2*v); converts at epilogue
// R4 structure (M=32/wave, 16KB stage quantum) with T3/T4 counted-vmcnt loop:
//   compute -> s_barrier(A) -> issue stage(kt+2) -> s_waitcnt vmcnt(4) -> s_barrier(B)
// Stage loads stay in flight ACROSS barriers (never vmcnt(0) mid-loop); barrier A proves
// all waves' MFMAs consumed buf[b] before its overwrite is issued; vmcnt(4)+B prove tile
// kt+1 resident for next iter (in-order vmcnt semantics).
// XCD-aware remap keeps a row-tile's 4 quarter-blocks on one XCD's L2.
__global__ __launch_bounds__(256)
void k_passA(const unsigned short* __restrict__ resh,
             const unsigned short* __restrict__ ehf,   // level slice, fragment-major
             const float* __restrict__ e2n,            // level slice, -0.5*e2
             float* __restrict__ pb1,                  // [4][B] best score
             int* __restrict__ pk1,                    // [4][B] best k
             float* __restrict__ ps2)                  // [4][B] second best
{
    __shared__ unsigned short btile[2][8192];
    __shared__ float e2t[512];

    const int tid = threadIdx.x;
    const int w = tid >> 6;
    const int lane = tid & 63;
    const int kloc = lane & 15;
    const int quad = lane >> 4;

    // remap: xcd = j&7 (HW round-robin), quarter cycles fastest within an XCD
    const int j = blockIdx.x;                  // grid = 2048, 2048%8==0 -> bijective
    const int xcd = j & 7;
    const int within = j >> 3;                 // [0,256)
    const int quarter = within & 3;
    const int rowtile = xcd * 64 + (within >> 2);   // [0,512)
    const int rowbase = rowtile * 128 + w * 32;
    const int r16 = rowbase >> 4;

    const char* src = (const char*)(const void*)(ehf + (size_t)quarter * (512 * ND));

    // prologue: async-stage tiles 0,1 (latency hides under ah/e2t loads below)
    stage16k(src,         (char*)&btile[0][0], w, lane);
    stage16k(src + 16384, (char*)&btile[1][0], w, lane);

    // A fragments: 16 coalesced 16B loads (prologue hoisted into k_res16)
    v8h ah[2][8];
    const v8h* rhp = (const v8h*)(const void*)resh;
    #pragma unroll
    for (int m = 0; m < 2; ++m) {
        #pragma unroll
        for (int dc = 0; dc < 8; ++dc)
            ah[m][dc] = rhp[((size_t)(r16 + m) * 8 + dc) * 64 + lane];
    }

    // -0.5*e2 slice for this K-quarter into LDS (broadcast reads, conflict-free)
    e2t[tid] = e2n[quarter * 512 + tid];
    e2t[256 + tid] = e2n[quarter * 512 + 256 + tid];

    float m1[8], m2[8];
    int k1[8];
    #pragma unroll
    for (int s = 0; s < 8; ++s) { m1[s] = -3.0e38f; m2[s] = -3.0e38f; k1[s] = 0; }

    __syncthreads();   // full drain once: tiles 0,1 + e2t + ah resident

    #pragma unroll 1
    for (int kt = 0; kt < 16; ++kt) {
        const int b = kt & 1;
        #pragma unroll
        for (int nt = 0; nt < 2; ++nt) {
            const int klq = kt * 32 + nt * 16 + kloc;     // k within quarter
            const float e2h = e2t[klq];
            const v4f cinit = {e2h, e2h, e2h, e2h};
            v4f a0a, a1a;
            v4f a0b = {0.f, 0.f, 0.f, 0.f}, a1b = {0.f, 0.f, 0.f, 0.f};
            {
                const v8h bh = *(const v8h*)(const void*)&btile[b][((nt * 8 + 0) * 64 + quad * 16 + kloc) * 8];
                a0a = __builtin_amdgcn_mfma_f32_16x16x32_f16(ah[0][0], bh, cinit, 0, 0, 0);
                a1a = __builtin_amdgcn_mfma_f32_16x16x32_f16(ah[1][0], bh, cinit, 0, 0, 0);
            }
            #pragma unroll
            for (int dc = 1; dc < 4; ++dc) {
                const v8h bh = *(const v8h*)(const void*)&btile[b][((nt * 8 + dc) * 64 + quad * 16 + kloc) * 8];
                a0a = __builtin_amdgcn_mfma_f32_16x16x32_f16(ah[0][dc], bh, a0a, 0, 0, 0);
                a1a = __builtin_amdgcn_mfma_f32_16x16x32_f16(ah[1][dc], bh, a1a, 0, 0, 0);
            }
            #pragma unroll
            for (int dc = 4; dc < 8; ++dc) {
                const v8h bh = *(const v8h*)(const void*)&btile[b][((nt * 8 + dc) * 64 + quad * 16 + kloc) * 8];
                a0b = __builtin_amdgcn_mfma_f32_16x16x32_f16(ah[0][dc], bh, a0b, 0, 0, 0);
                a1b = __builtin_amdgcn_mfma_f32_16x16x32_f16(ah[1][dc], bh, a1b, 0, 0, 0);
            }
            const int kglob = quarter * 512 + klq;
            #pragma unroll
            for (int reg = 0; reg < 4; ++reg) {
                const float v0 = a0a[reg] + a0b[reg];
                const bool g0 = v0 > m1[reg];
                m2[reg] = __builtin_amdgcn_fmed3f(v0, m1[reg], m2[reg]);  // = max(m2, min(m1, v0))
                m1[reg] = fmaxf(m1[reg], v0);
                k1[reg] = g0 ? kglob : k1[reg];
                const float v1 = a1a[reg] + a1b[reg];
                const bool g1 = v1 > m1[4 + reg];
                m2[4 + reg] = __builtin_amdgcn_fmed3f(v1, m1[4 + reg], m2[4 + reg]);
                m1[4 + reg] = fmaxf(m1[4 + reg], v1);
                k1[4 + reg] = g1 ? kglob : k1[4 + reg];
            }
        }
        // ---- T3/T4 phase boundary: no vmcnt(0) mid-loop ----
        __builtin_amdgcn_sched_barrier(0);
        __builtin_amdgcn_s_barrier();            // A: all waves consumed btile[b]
        __builtin_amdgcn_sched_barrier(0);
        if (kt + 2 < 16)
            stage16k(src + (size_t)(kt + 2) * 16384, (char*)&btile[b][0], w, lane);
        __builtin_amdgcn_sched_barrier(0);
        if (kt == 14) { asm volatile("s_waitcnt vmcnt(0)" ::: "memory"); }  // last tile: no stage(16) behind it
        else          { asm volatile("s_waitcnt vmcnt(4)" ::: "memory"); }  // own stage(kt+1) landed; stage(kt+2) in flight
        __builtin_amdgcn_s_barrier();            // B: tile kt+1 resident for every wave
        __builtin_amdgcn_sched_barrier(0);
    }

    // 16-lane max-reduction (tie-breaks irrelevant: within-THRM ties go to exact rerank)
    #pragma unroll
    for (int off = 1; off < 16; off <<= 1) {
        #pragma unroll
        for (int s = 0; s < 8; ++s) {
            const float o1 = __shfl_xor(m1[s], off, 16);
            const float o2 = __shfl_xor(m2[s], off, 16);
            const int   ok = __shfl_xor(k1[s], off, 16);
            const float lo = fminf(m1[s], o1);
            m2[s] = fmaxf(fmaxf(m2[s], o2), lo);
            k1[s] = (o1 > m1[s]) ? ok : k1[s];
            m1[s] = fmaxf(m1[s], o1);
        }
    }
    if (kloc == 0) {
        #pragma unroll
        for (int s = 0; s < 8; ++s) {
            const int m = s >> 2, reg = s & 3;
            const int row = rowbase + m * 16 + quad * 4 + reg;
            pb1[(size_t)quarter * NB + row] = -2.0f * m1[s];
            pk1[(size_t)quarter * NB + row] = k1[s];
            ps2[(size_t)quarter * NB + row] = -2.0f * m2[s];
        }
    }
}

// ---------------- merge 4 K-quarters (float compares — scores can be negative!) ----------
__global__ void k_margin(const float* __restrict__ pb1, const int* __restrict__ pk1,
                         const float* __restrict__ ps2,
                         int* __restrict__ idx_l, float* __restrict__ codes,
                         int* __restrict__ ulist, int* __restrict__ cnt, int level)
{
    const int row = blockIdx.x * 256 + threadIdx.x;
    float b1 = pb1[row];
    int   k  = pk1[row];
    float b2 = ps2[row];
    #pragma unroll
    for (int p = 1; p < 4; ++p) {
        const float c1 = pb1[(size_t)p * NB + row];
        const float c2 = ps2[(size_t)p * NB + row];
        const int   ck = pk1[(size_t)p * NB + row];
        if (c1 < b1) { b2 = fminf(b1, c2); b1 = c1; k = ck; }
        else         { b2 = fminf(b2, c1); }
    }
    idx_l[row] = k;
    codes[(size_t)row * NL + level] = (float)k;
    if (b2 - b1 <= THRM) {
        int p = atomicAdd(cnt, 1);
        ulist[p] = row;
    }
}

// ---------------- rerank stage 1: exact scores (bit-exact validated path) ----------------
// emb read direct from L2 (no 64KB LDS stage -> occupancy no longer LDS-capped);
// x2 via 16-lane shfl_xor butterfly reproducing the exact pairwise-sum tree.
__global__ __launch_bounds__(256)
void k_rr1(const float* __restrict__ residual,
           const float* __restrict__ cb,
           const float* __restrict__ emb,
           const float* __restrict__ e2,
           const int* __restrict__ idx_hist,
           const int* __restrict__ ulist,
           const int* __restrict__ cnt,
           ull* __restrict__ partial,
           int level)
{
    __shared__ float resL[16 * 260];
    __shared__ float x2s[16];
    __shared__ int   urows[16];
    __shared__ ull   redM[16][17];

    const int t = threadIdx.x;
    const int ks = blockIdx.x & 31;
    const int rt0 = blockIdx.x >> 5;
    const int n = *cnt;
    const int nrt = (n + 15) >> 4;
    if (rt0 >= nrt) return;

    const int row = t & 15;
    const int kg = t >> 4;
    float e2r[4];
    #pragma unroll
    for (int j = 0; j < 4; ++j) e2r[j] = e2[ks * 64 + kg * 4 + j];
    const float* ep = emb + (size_t)(ks * 64 + kg * 4) * ND;

    for (int rt = rt0; rt < nrt; rt += 64) {
        __syncthreads();
        if (t < 16) {
            const int i = rt * 16 + t;
            urows[t] = ulist[(i < n) ? i : rt * 16];
        }
        __syncthreads();
        #pragma unroll
        for (int i = 0; i < 4; ++i) {
            const int fi = t + 256 * i;
            const int r = fi >> 6, q = fi & 63;
            const int ur = urows[r];
            float4 v = ((const float4*)residual)[(size_t)ur * 64 + q];
            for (int j = 0; j < level; ++j) {
                const int kp = idx_hist[j * NB + ur];
                const float4 qv = ((const float4*)cb)[(size_t)(j * NK + kp) * 64 + q];
                v.x = __fsub_rn(v.x, qv.x);
                v.y = __fsub_rn(v.y, qv.y);
                v.z = __fsub_rn(v.z, qv.z);
                v.w = __fsub_rn(v.w, qv.w);
            }
            *(float4*)&resL[r * 260 + q * 4] = v;
        }
        __syncthreads();
        {
            // 16 lanes per row: lane (h, jj) owns accumulator r8[jj] of half h
            // (identical __fmul_rn/__fadd_rn chain), then xor-butterfly combines in
            // the exact tree order ((01)+(23))+((45)+(67)), then halves[0]+halves[1].
            const int xr = t >> 4;
            const int h = (t >> 3) & 1;
            const int jj = t & 7;
            const float* p = &resL[xr * 260 + h * 128];
            float v = __fmul_rn(p[jj], p[jj]);
            for (int i = 8; i < 128; i += 8)
                v = __fadd_rn(v, __fmul_rn(p[i + jj], p[i + jj]));
            v = __fadd_rn(v, __shfl_xor(v, 1, 16));
            v = __fadd_rn(v, __shfl_xor(v, 2, 16));
            v = __fadd_rn(v, __shfl_xor(v, 4, 16));
            v = __fadd_rn(v, __shfl_xor(v, 8, 16));
            if ((t & 15) == 0) x2s[xr] = v;
        }
        __syncthreads();

        float d0 = 0.f, d1 = 0.f, d2 = 0.f, d3 = 0.f;
        const float* rp = &resL[row * 260];
        #pragma unroll 4
        for (int q = 0; q < 64; ++q) {
            const float4 rv = *(const float4*)&rp[q * 4];
            const float4 e0 = *(const float4*)&ep[q * 4];
            const float4 e1 = *(const float4*)&ep[ND + q * 4];
            const float4 ee2 = *(const float4*)&ep[2 * ND + q * 4];
            const float4 e3 = *(const float4*)&ep[3 * ND + q * 4];
            d0 = __fmaf_rn(rv.x, e0.x, d0); d0 = __fmaf_rn(rv.y, e0.y, d0);
            d0 = __fmaf_rn(rv.z, e0.z, d0); d0 = __fmaf_rn(rv.w, e0.w, d0);
            d1 = __fmaf_rn(rv.x, e1.x, d1); d1 = __fmaf_rn(rv.y, e1.y, d1);
            d1 = __fmaf_rn(rv.z, e1.z, d1); d1 = __fmaf_rn(rv.w, e1.w, d1);
            d2 = __fmaf_rn(rv.x, ee2.x, d2); d2 = __fmaf_rn(rv.y, ee2.y, d2);
            d2 = __fmaf_rn(rv.z, ee2.z, d2); d2 = __fmaf_rn(rv.w, ee2.w, d2);
            d3 = __fmaf_rn(rv.x, e3.x, d3); d3 = __fmaf_rn(rv.y, e3.y, d3);
            d3 = __fmaf_rn(rv.z, e3.z, d3); d3 = __fmaf_rn(rv.w, e3.w, d3);
        }

        const float x2v = x2s[row];
        const int kb = ks * 64 + kg * 4;
        float s;
        ull best, u;
        s = __fsub_rn(__fadd_rn(x2v, e2r[0]), __fmul_rn(2.0f, d0));
        best = ((ull)__float_as_uint(s) << 32) | (ull)(kb + 0);
        s = __fsub_rn(__fadd_rn(x2v, e2r[1]), __fmul_rn(2.0f, d1));
        u = ((ull)__float_as_uint(s) << 32) | (ull)(kb + 1);
        if (u < best) best = u;
        s = __fsub_rn(__fadd_rn(x2v, e2r[2]), __fmul_rn(2.0f, d2));
        u = ((ull)__float_as_uint(s) << 32) | (ull)(kb + 2);
        if (u < best) best = u;
        s = __fsub_rn(__fadd_rn(x2v, e2r[3]), __fmul_rn(2.0f, d3));
        u = ((ull)__float_as_uint(s) << 32) | (ull)(kb + 3);
        if (u < best) best = u;

        redM[row][kg] = best;
        __syncthreads();
        if (t < 16) {
            ull b = redM[t][0];
            #pragma unroll
            for (int g = 1; g < 16; ++g) { const ull v = redM[t][g]; if (v < b) b = v; }
            partial[(size_t)(rt * 16 + t) * 32 + ks] = b;
        }
    }
}

// ---------------- rerank stage 2: reduce 32 k-slices per uncertain row ----------------
__global__ void k_rr2(const ull* __restrict__ partial,
                      const int* __restrict__ ulist,
                      const int* __restrict__ cnt,
                      int* __restrict__ idx_l,
                      float* __restrict__ codes,
                      int level)
{
    const int n = *cnt;
    for (int i = blockIdx.x * 256 + threadIdx.x; i < n; i += gridDim.x * 256) {
        const ull* p = &partial[(size_t)i * 32];
        ull b = p[0];
        #pragma unroll
        for (int s2 = 1; s2 < 32; ++s2) { const ull v = p[s2]; if (v < b) b = v; }
        const int k = (int)(b & 0xffffffffull);
        const int row = ulist[i];
        idx_l[row] = k;
        codes[(size_t)row * NL + level] = (float)k;
    }
}

// ---------------- finalize: quantized = fadd chain q0+q1+q2+q3 (reference order) ----------------
__global__ void k_finalize(const float* __restrict__ cb, const int* __restrict__ idx_hist,
                           float4* __restrict__ outq) {
    const int i = blockIdx.x * 256 + threadIdx.x;
    const int r = i >> 6, c = i & 63;
    const float4* cb4 = (const float4*)cb;
    const int i0 = idx_hist[r];
    const int i1 = idx_hist[NB + r];
    const int i2 = idx_hist[2 * NB + r];
    const int i3 = idx_hist[3 * NB + r];
    float4 q = cb4[(size_t)i0 * 64 + c];
    float4 t1 = cb4[(size_t)(NK + i1) * 64 + c];
    q.x = __fadd_rn(q.x, t1.x); q.y = __fadd_rn(q.y, t1.y);
    q.z = __fadd_rn(q.z, t1.z); q.w = __fadd_rn(q.w, t1.w);
    float4 t2 = cb4[(size_t)(2 * NK + i2) * 64 + c];
    q.x = __fadd_rn(q.x, t2.x); q.y = __fadd_rn(q.y, t2.y);
    q.z = __fadd_rn(q.z, t2.z); q.w = __fadd_rn(q.w, t2.w);
    float4 t3 = cb4[(size_t)(3 * NK + i3) * 64 + c];
    q.x = __fadd_rn(q.x, t3.x); q.y = __fadd_rn(q.y, t3.y);
    q.z = __fadd_rn(q.z, t3.z); q.w = __fadd_rn(q.w, t3.w);
    outq[i] = q;
}

extern "C" void kernel_launch(void* const* d_in, const int* in_sizes, int n_in,
                              void* d_out, int out_size, void* d_ws, size_t ws_size,
                              hipStream_t stream) {
    const float* residual = (const float*)d_in[0];
    const float* cb = (const float*)d_in[1];

    float* pb1 = (float*)d_ws;                                   // [4][B] 1 MB
    int* pk1 = (int*)(pb1 + 4 * (size_t)NB);                     // [4][B] 1 MB
    float* ps2 = (float*)(pk1 + 4 * (size_t)NB);                 // [4][B] 1 MB
    ull* partial = (ull*)(ps2 + 4 * (size_t)NB);                 // 16.8 MB
    float* e2 = (float*)(partial + (size_t)(NB + 16) * 32);      // 32 KB
    float* e2n = e2 + (size_t)NL * NK;                           // 32 KB
    int* idx_hist = (int*)(e2n + (size_t)NL * NK);               // [L][B] 1 MB
    int* ulist = idx_hist + (size_t)NL * NB;                     // 256 KB
    int* cnt = ulist + NB;
    unsigned short* ehf = (unsigned short*)(cnt + 64);           // fp16 frag-major 4 MB
    unsigned short* resh = ehf + (size_t)NL * NK * ND;           // fp16 residual frags 32 MB

    float* codes = (float*)d_out + (size_t)NB * ND;              // fp32 [B, L]

    k_zero<<<1, 64, 0, stream>>>(cnt);
    k_e2<<<NL * NK / 32, 64, 0, stream>>>(cb, e2, e2n);
    k_split16<<<NL * NK * 32 / 256, 256, 0, stream>>>(cb, ehf);

    for (int l = 0; l < NL; ++l) {
        const unsigned short* ehl = ehf + (size_t)l * NK * ND;
        const float* e2l = e2 + (size_t)l * NK;
        const float* e2nl = e2n + (size_t)l * NK;
        int* idx_l = idx_hist + (size_t)l * NB;
        k_res16<<<NB * ND / 8 / 256, 256, 0, stream>>>(residual, cb, idx_hist, resh, l);
        k_passA<<<NB / 128 * 4, 256, 0, stream>>>(resh, ehl, e2nl, pb1, pk1, ps2);
        k_margin<<<NB / 256, 256, 0, stream>>>(pb1, pk1, ps2, idx_l, codes, ulist, cnt + l, l);
        k_rr1<<<2048, 256, 0, stream>>>(residual, cb, cb + (size_t)l * NK * ND, e2l,
                                        idx_hist, ulist, cnt + l, partial, l);
        k_rr2<<<64, 256, 0, stream>>>(partial, ulist, cnt + l, idx_l, codes, l);
    }
    k_finalize<<<NB * ND / 4 / 256, 256, 0, stream>>>(cb, idx_hist, (float4*)d_out);
}